// Round 2
// baseline (224.395 us; speedup 1.0000x reference)
//
#include <hip/hip_runtime.h>
#include <hip/hip_bf16.h>
#include <math.h>

#define HDIM 2048
#define KDIM 2048
#define SDIM 8192
#define VDIM 2048

using short8 = __attribute__((ext_vector_type(8))) short;
using f32x4  = __attribute__((ext_vector_type(4))) float;
using us4    = __attribute__((ext_vector_type(4))) unsigned short;

__device__ __forceinline__ unsigned short f2bf(float f) {
  union { float f; unsigned int u; } x; x.f = f;
  unsigned int r = x.u + 0x7fffu + ((x.u >> 16) & 1u);  // RNE
  return (unsigned short)(r >> 16);
}

// ---------------- kernel 1: pq[h] = sum_q query[q] * Wq[h,q] ----------------
__global__ __launch_bounds__(256) void pq_kernel(const float* __restrict__ query,
                                                 const float* __restrict__ Wq,
                                                 float* __restrict__ pq) {
  int wave = threadIdx.x >> 6, lane = threadIdx.x & 63;
  int h = blockIdx.x * 4 + wave;
  const float* w = Wq + (size_t)h * KDIM;
  float s = 0.f;
  for (int i = lane; i < KDIM; i += 64) s = fmaf(query[i], w[i], s);
  #pragma unroll
  for (int off = 32; off; off >>= 1) s += __shfl_xor(s, off);
  if (lane == 0) pq[h] = s;
}

// ---- kernel 2: fused  partial[s,hb] = sum_{h in block hb} Ws[h]*tanh(pq[h]+key[s,:]@Wk[h,:]) ----
// 128x128 tile over (s,h), K-loop in steps of 32, bf16 MFMA 16x16x32, 4 waves (2x2).
__global__ __launch_bounds__(256) void scores_kernel(const float* __restrict__ key,
                                                     const float* __restrict__ Wk,
                                                     const float* __restrict__ pq,
                                                     const float* __restrict__ Ws,
                                                     float* __restrict__ partial) {
  __shared__ unsigned short As[128][40];  // +8 pad keeps 16B align, 2-way banks only
  __shared__ unsigned short Bs[128][40];
  __shared__ float sred[128][2];          // cross-wave (wn) score reduction

  const int tid  = threadIdx.x;
  const int s0   = blockIdx.x * 128;
  const int h0   = blockIdx.y * 128;
  const int wave = tid >> 6, lane = tid & 63;
  const int wm = wave >> 1, wn = wave & 1;       // 2x2 waves, each 64x64 out
  const int l16 = lane & 15, g16 = lane >> 4;

  // staging map: thread loads 4x float4 (one per row-group), rows 0..127, cols 4*(t&7)
  const int lrow = tid >> 3;          // 0..31
  const int lcol = (tid & 7) * 4;     // 0..28

  f32x4 acc[4][4];
  #pragma unroll
  for (int m = 0; m < 4; ++m)
    #pragma unroll
    for (int n = 0; n < 4; ++n) acc[m][n] = (f32x4)(0.0f);

  for (int k0 = 0; k0 < KDIM; k0 += 32) {
    __syncthreads();   // previous iteration's reads done before overwrite
    #pragma unroll
    for (int g = 0; g < 4; ++g) {
      int row = lrow + g * 32;
      f32x4 av = *(const f32x4*)&key[(size_t)(s0 + row) * KDIM + k0 + lcol];
      f32x4 bv = *(const f32x4*)&Wk[(size_t)(h0 + row) * KDIM + k0 + lcol];
      us4 ua, ub;
      #pragma unroll
      for (int j = 0; j < 4; ++j) { ua[j] = f2bf(av[j]); ub[j] = f2bf(bv[j]); }
      *(us4*)&As[row][lcol] = ua;
      *(us4*)&Bs[row][lcol] = ub;
    }
    __syncthreads();

    short8 a[4], b[4];
    #pragma unroll
    for (int m = 0; m < 4; ++m)
      a[m] = *(const short8*)&As[wm * 64 + m * 16 + l16][g16 * 8];
    #pragma unroll
    for (int n = 0; n < 4; ++n)
      b[n] = *(const short8*)&Bs[wn * 64 + n * 16 + l16][g16 * 8];

    #pragma unroll
    for (int m = 0; m < 4; ++m)
      #pragma unroll
      for (int n = 0; n < 4; ++n)
        acc[m][n] = __builtin_amdgcn_mfma_f32_16x16x32_bf16(a[m], b[n], acc[m][n], 0, 0, 0);
  }

  // epilogue: h = h0 + wn*64 + n*16 + l16 ; s-row = s0 + wm*64 + m*16 + g16*4 + j
  float pqv[4], wsv[4];
  #pragma unroll
  for (int n = 0; n < 4; ++n) {
    int h = h0 + wn * 64 + n * 16 + l16;
    pqv[n] = pq[h];
    wsv[n] = Ws[h];
  }

  #pragma unroll
  for (int m = 0; m < 4; ++m) {
    #pragma unroll
    for (int j = 0; j < 4; ++j) {
      float rs = 0.f;
      #pragma unroll
      for (int n = 0; n < 4; ++n)
        rs += tanhf(acc[m][n][j] + pqv[n]) * wsv[n];
      rs += __shfl_xor(rs, 1);
      rs += __shfl_xor(rs, 2);
      rs += __shfl_xor(rs, 4);
      rs += __shfl_xor(rs, 8);
      if (l16 == 0) {
        // per-wave 64-h partial for row (wm*64 + m*16 + g16*4 + j); wn halves
        sred[wm * 64 + m * 16 + g16 * 4 + j][wn] = rs;
      }
    }
  }
  __syncthreads();
  if (tid < 128) {
    float v = sred[tid][0] + sred[tid][1];
    partial[(size_t)(s0 + tid) * 16 + blockIdx.y] = v;
  }
}

// ---------------- kernel 3: softmax over S=8192 (single block) ----------------
__global__ __launch_bounds__(1024) void softmax_kernel(const float* __restrict__ partial,
                                                       float* __restrict__ weights) {
  __shared__ float red[16];
  int tid = threadIdx.x;
  int sbase = tid * 8;
  float sc[8];
  float mx = -1e30f;
  #pragma unroll
  for (int i = 0; i < 8; ++i) {
    const float* p = partial + (size_t)(sbase + i) * 16;
    float v = 0.f;
    #pragma unroll
    for (int q = 0; q < 16; ++q) v += p[q];
    sc[i] = v;
    mx = fmaxf(mx, v);
  }
  #pragma unroll
  for (int off = 32; off; off >>= 1) mx = fmaxf(mx, __shfl_xor(mx, off));
  if ((tid & 63) == 0) red[tid >> 6] = mx;
  __syncthreads();
  float gmx = red[0];
  #pragma unroll
  for (int q = 1; q < 16; ++q) gmx = fmaxf(gmx, red[q]);
  __syncthreads();
  float ls = 0.f;
  #pragma unroll
  for (int i = 0; i < 8; ++i) { sc[i] = expf(sc[i] - gmx); ls += sc[i]; }
  #pragma unroll
  for (int off = 32; off; off >>= 1) ls += __shfl_xor(ls, off);
  if ((tid & 63) == 0) red[tid >> 6] = ls;
  __syncthreads();
  float gs = 0.f;
  #pragma unroll
  for (int q = 0; q < 16; ++q) gs += red[q];
  float inv = 1.0f / gs;
  #pragma unroll
  for (int i = 0; i < 8; ++i) weights[sbase + i] = sc[i] * inv;
}

// ---------------- kernel 4: context partials over s-chunks ----------------
__global__ __launch_bounds__(256) void ctx_partial_kernel(const float* __restrict__ values,
                                                          const float* __restrict__ w,
                                                          float* __restrict__ part) {
  int vcol = blockIdx.x * 256 + threadIdx.x;
  int ss0 = blockIdx.y * 256;
  float acc = 0.f;
  for (int s = ss0; s < ss0 + 256; ++s)
    acc = fmaf(w[s], values[(size_t)s * VDIM + vcol], acc);
  part[(size_t)blockIdx.y * VDIM + vcol] = acc;
}

// ---------------- kernel 5: context reduce ----------------
__global__ __launch_bounds__(256) void ctx_reduce_kernel(const float* __restrict__ part,
                                                         float* __restrict__ ctx) {
  int vcol = blockIdx.x * 256 + threadIdx.x;
  float acc = 0.f;
  #pragma unroll
  for (int p = 0; p < 32; ++p) acc += part[(size_t)p * VDIM + vcol];
  ctx[vcol] = acc;
}

extern "C" void kernel_launch(void* const* d_in, const int* in_sizes, int n_in,
                              void* d_out, int out_size, void* d_ws, size_t ws_size,
                              hipStream_t stream) {
  const float* query  = (const float*)d_in[0];
  const float* key    = (const float*)d_in[1];
  const float* values = (const float*)d_in[2];
  const float* Wq     = (const float*)d_in[3];
  const float* Wk     = (const float*)d_in[4];
  const float* Ws     = (const float*)d_in[5];

  float* out     = (float*)d_out;
  float* weights = out;          // [8192]
  float* ctx     = out + SDIM;   // [2048]

  char*  ws      = (char*)d_ws;
  float* pq      = (float*)ws;                   // 2048 f32
  float* partial = (float*)(ws + 8192);          // 8192*16 f32 (512 KiB)
  // cpart aliases partial: partial is fully consumed by softmax before kernel 4
  float* cpart   = partial;                      // 32*2048 f32 (256 KiB)

  pq_kernel<<<HDIM / 4, 256, 0, stream>>>(query, Wq, pq);
  scores_kernel<<<dim3(SDIM / 128, HDIM / 128), 256, 0, stream>>>(key, Wk, pq, Ws, partial);
  softmax_kernel<<<1, 1024, 0, stream>>>(partial, weights);
  ctx_partial_kernel<<<dim3(VDIM / 256, 32), 256, 0, stream>>>(values, weights, cpart);
  ctx_reduce_kernel<<<VDIM / 256, 256, 0, stream>>>(cpart, ctx);
}

// Round 3
// 183.870 us; speedup vs baseline: 1.2204x; 1.2204x over previous
//
#include <hip/hip_runtime.h>
#include <hip/hip_bf16.h>
#include <math.h>

#define HDIM 2048
#define KDIM 2048
#define SDIM 8192
#define VDIM 2048
#define BK   32

using short8 = __attribute__((ext_vector_type(8))) short;
using f32x4  = __attribute__((ext_vector_type(4))) float;
using us4    = __attribute__((ext_vector_type(4))) unsigned short;
using us8    = __attribute__((ext_vector_type(8))) unsigned short;

typedef const __attribute__((address_space(1))) void g_void;
typedef __attribute__((address_space(3))) void lds_void;

__device__ __forceinline__ unsigned short f2bf(float f) {
  union { float f; unsigned int u; } x; x.f = f;
  unsigned int r = x.u + 0x7fffu + ((x.u >> 16) & 1u);  // RNE
  return (unsigned short)(r >> 16);
}

// ---------------- kernel 0: f32 -> bf16 convert (8 elems/thread) ----------------
__global__ __launch_bounds__(256) void cvt_kernel(const float* __restrict__ in,
                                                  unsigned short* __restrict__ out,
                                                  int n8) {
  int i = blockIdx.x * 256 + threadIdx.x;
  if (i >= n8) return;
  f32x4 a = *(const f32x4*)&in[(size_t)i * 8];
  f32x4 b = *(const f32x4*)&in[(size_t)i * 8 + 4];
  us8 o;
  #pragma unroll
  for (int j = 0; j < 4; ++j) { o[j] = f2bf(a[j]); o[j + 4] = f2bf(b[j]); }
  *(us8*)&out[(size_t)i * 8] = o;
}

// ---------------- kernel 1: pq[h] = sum_q query[q] * Wq[h,q] ----------------
__global__ __launch_bounds__(256) void pq_kernel(const float* __restrict__ query,
                                                 const float* __restrict__ Wq,
                                                 float* __restrict__ pq) {
  int wave = threadIdx.x >> 6, lane = threadIdx.x & 63;
  int h = blockIdx.x * 4 + wave;
  const float* w = Wq + (size_t)h * KDIM;
  float s = 0.f;
  for (int i = lane; i < KDIM; i += 64) s = fmaf(query[i], w[i], s);
  #pragma unroll
  for (int off = 32; off; off >>= 1) s += __shfl_xor(s, off);
  if (lane == 0) pq[h] = s;
}

// ---- kernel 2: fused  partial[s,hb] = sum_{h in blk} Ws[h]*tanh(pq[h]+key[s,:]@Wk[h,:]) ----
// m97 structure: 128x128 tile, BK=32, global_load_lds width 16, linear LDS, 2 barriers/K-step.
__global__ __launch_bounds__(256) void scores_kernel(const unsigned short* __restrict__ keybf,
                                                     const unsigned short* __restrict__ wkbf,
                                                     const float* __restrict__ pq,
                                                     const float* __restrict__ Ws,
                                                     float* __restrict__ partial) {
  __shared__ unsigned short As[128][BK];   // 8 KB, linear (global_load_lds dest)
  __shared__ unsigned short Bs[128][BK];   // 8 KB
  __shared__ float sred[128][2];

  const int tid  = threadIdx.x;
  const int s0   = blockIdx.x * 128;
  const int h0   = blockIdx.y * 128;
  const int wave = tid >> 6, lane = tid & 63;
  const int wm = wave >> 1, wn = wave & 1;       // 2x2 waves, each 64x64 out
  const int l16 = lane & 15, g16 = lane >> 4;

  // staging map: wave stages 16-row chunks; lane l -> row l/4, 16B col chunk l%4
  const int lrow = lane >> 2;            // 0..15
  const int lcolb = (lane & 3) * 16;     // byte col: 0/16/32/48  (row = 64B)

  const char* aRow0 = (const char*)keybf + ((size_t)(s0 + wave * 16 + lrow) * KDIM) * 2 + lcolb;
  const char* aRow1 = aRow0 + (size_t)64 * KDIM * 2;
  const char* bRow0 = (const char*)wkbf + ((size_t)(h0 + wave * 16 + lrow) * KDIM) * 2 + lcolb;
  const char* bRow1 = bRow0 + (size_t)64 * KDIM * 2;

  lds_void* la0 = (lds_void*)((char*)As + wave * 1024);
  lds_void* la1 = (lds_void*)((char*)As + 4096 + wave * 1024);
  lds_void* lb0 = (lds_void*)((char*)Bs + wave * 1024);
  lds_void* lb1 = (lds_void*)((char*)Bs + 4096 + wave * 1024);

  f32x4 acc[4][4];
  #pragma unroll
  for (int m = 0; m < 4; ++m)
    #pragma unroll
    for (int n = 0; n < 4; ++n) acc[m][n] = (f32x4)(0.0f);

  for (int k0 = 0; k0 < KDIM; k0 += BK) {
    __syncthreads();   // previous iteration's LDS reads done before overwrite
    const size_t kb = (size_t)k0 * 2;
    __builtin_amdgcn_global_load_lds((g_void*)(aRow0 + kb), la0, 16, 0, 0);
    __builtin_amdgcn_global_load_lds((g_void*)(aRow1 + kb), la1, 16, 0, 0);
    __builtin_amdgcn_global_load_lds((g_void*)(bRow0 + kb), lb0, 16, 0, 0);
    __builtin_amdgcn_global_load_lds((g_void*)(bRow1 + kb), lb1, 16, 0, 0);
    __syncthreads();   // compiler emits vmcnt(0) drain before barrier

    short8 a[4], b[4];
    #pragma unroll
    for (int m = 0; m < 4; ++m)
      a[m] = *(const short8*)&As[wm * 64 + m * 16 + l16][g16 * 8];
    #pragma unroll
    for (int n = 0; n < 4; ++n)
      b[n] = *(const short8*)&Bs[wn * 64 + n * 16 + l16][g16 * 8];

    #pragma unroll
    for (int m = 0; m < 4; ++m)
      #pragma unroll
      for (int n = 0; n < 4; ++n)
        acc[m][n] = __builtin_amdgcn_mfma_f32_16x16x32_bf16(a[m], b[n], acc[m][n], 0, 0, 0);
  }

  // epilogue: h = h0 + wn*64 + n*16 + l16 ; s-row = s0 + wm*64 + m*16 + g16*4 + j
  float pqv[4], wsv[4];
  #pragma unroll
  for (int n = 0; n < 4; ++n) {
    int h = h0 + wn * 64 + n * 16 + l16;
    pqv[n] = pq[h];
    wsv[n] = Ws[h];
  }

  #pragma unroll
  for (int m = 0; m < 4; ++m) {
    #pragma unroll
    for (int j = 0; j < 4; ++j) {
      float rs = 0.f;
      #pragma unroll
      for (int n = 0; n < 4; ++n)
        rs += tanhf(acc[m][n][j] + pqv[n]) * wsv[n];
      rs += __shfl_xor(rs, 1);
      rs += __shfl_xor(rs, 2);
      rs += __shfl_xor(rs, 4);
      rs += __shfl_xor(rs, 8);
      if (l16 == 0)
        sred[wm * 64 + m * 16 + g16 * 4 + j][wn] = rs;
    }
  }
  __syncthreads();
  if (tid < 128) {
    float v = sred[tid][0] + sred[tid][1];
    partial[(size_t)(s0 + tid) * 16 + blockIdx.y] = v;
  }
}

// ---------------- kernel 3: softmax over S=8192 (single block) ----------------
__global__ __launch_bounds__(1024) void softmax_kernel(const float* __restrict__ partial,
                                                       float* __restrict__ weights) {
  __shared__ float red[16];
  int tid = threadIdx.x;
  int sbase = tid * 8;
  float sc[8];
  float mx = -1e30f;
  #pragma unroll
  for (int i = 0; i < 8; ++i) {
    const float* p = partial + (size_t)(sbase + i) * 16;
    float v = 0.f;
    #pragma unroll
    for (int q = 0; q < 16; ++q) v += p[q];
    sc[i] = v;
    mx = fmaxf(mx, v);
  }
  #pragma unroll
  for (int off = 32; off; off >>= 1) mx = fmaxf(mx, __shfl_xor(mx, off));
  if ((tid & 63) == 0) red[tid >> 6] = mx;
  __syncthreads();
  float gmx = red[0];
  #pragma unroll
  for (int q = 1; q < 16; ++q) gmx = fmaxf(gmx, red[q]);
  __syncthreads();
  float ls = 0.f;
  #pragma unroll
  for (int i = 0; i < 8; ++i) { sc[i] = expf(sc[i] - gmx); ls += sc[i]; }
  #pragma unroll
  for (int off = 32; off; off >>= 1) ls += __shfl_xor(ls, off);
  if ((tid & 63) == 0) red[tid >> 6] = ls;
  __syncthreads();
  float gs = 0.f;
  #pragma unroll
  for (int q = 0; q < 16; ++q) gs += red[q];
  float inv = 1.0f / gs;
  #pragma unroll
  for (int i = 0; i < 8; ++i) weights[sbase + i] = sc[i] * inv;
}

// ---------------- kernel 4: context partials (float4, 128-row chunks) ----------------
__global__ __launch_bounds__(256) void ctx_partial_kernel(const float* __restrict__ values,
                                                          const float* __restrict__ w,
                                                          float* __restrict__ part) {
  int vcol4 = blockIdx.x * 256 + threadIdx.x;   // float4 column index, 0..511
  int ss0 = blockIdx.y * 128;
  f32x4 acc = (f32x4)(0.0f);
  for (int s = ss0; s < ss0 + 128; ++s) {
    f32x4 v = *(const f32x4*)&values[(size_t)s * VDIM + vcol4 * 4];
    float ws = w[s];
    #pragma unroll
    for (int j = 0; j < 4; ++j) acc[j] = fmaf(ws, v[j], acc[j]);
  }
  *(f32x4*)&part[(size_t)blockIdx.y * VDIM + vcol4 * 4] = acc;
}

// ---------------- kernel 5: context reduce ----------------
__global__ __launch_bounds__(256) void ctx_reduce_kernel(const float* __restrict__ part,
                                                         float* __restrict__ ctx) {
  int vcol = blockIdx.x * 256 + threadIdx.x;
  float acc = 0.f;
  #pragma unroll
  for (int p = 0; p < 64; ++p) acc += part[(size_t)p * VDIM + vcol];
  ctx[vcol] = acc;
}

extern "C" void kernel_launch(void* const* d_in, const int* in_sizes, int n_in,
                              void* d_out, int out_size, void* d_ws, size_t ws_size,
                              hipStream_t stream) {
  const float* query  = (const float*)d_in[0];
  const float* key    = (const float*)d_in[1];
  const float* values = (const float*)d_in[2];
  const float* Wq     = (const float*)d_in[3];
  const float* Wk     = (const float*)d_in[4];
  const float* Ws     = (const float*)d_in[5];

  float* out     = (float*)d_out;
  float* weights = out;          // [8192]
  float* ctx     = out + SDIM;   // [2048]

  char* ws = (char*)d_ws;
  unsigned short* keybf = (unsigned short*)ws;                        // S*K bf16 = 32 MiB
  unsigned short* wkbf  = (unsigned short*)(ws + (size_t)SDIM * KDIM * 2);  // H*K bf16 = 8 MiB
  char* tail = ws + (size_t)SDIM * KDIM * 2 + (size_t)HDIM * KDIM * 2;
  float* pq      = (float*)tail;                    // 2048 f32
  float* partial = (float*)(tail + 8192);           // 8192*16 f32 (512 KiB)
  float* cpart   = (float*)(tail + 8192 + (size_t)SDIM * 16 * 4);  // 64*2048 f32

  cvt_kernel<<<(SDIM * KDIM / 8 + 255) / 256, 256, 0, stream>>>(key, keybf, SDIM * KDIM / 8);
  cvt_kernel<<<(HDIM * KDIM / 8 + 255) / 256, 256, 0, stream>>>(Wk, wkbf, HDIM * KDIM / 8);
  pq_kernel<<<HDIM / 4, 256, 0, stream>>>(query, Wq, pq);
  scores_kernel<<<dim3(SDIM / 128, HDIM / 128), 256, 0, stream>>>(keybf, wkbf, pq, Ws, partial);
  softmax_kernel<<<1, 1024, 0, stream>>>(partial, weights);
  ctx_partial_kernel<<<dim3(VDIM / (256 * 4), 64), 256, 0, stream>>>(values, weights, cpart);
  ctx_reduce_kernel<<<VDIM / 256, 256, 0, stream>>>(cpart, ctx);
}

// Round 4
// 131.483 us; speedup vs baseline: 1.7066x; 1.3984x over previous
//
#include <hip/hip_runtime.h>
#include <hip/hip_bf16.h>
#include <math.h>

#define HDIM 2048
#define KDIM 2048
#define SDIM 8192
#define VDIM 2048
#define BKT  64
#define NT   (KDIM / BKT)   // 32 K-tiles

using short8 = __attribute__((ext_vector_type(8))) short;
using f32x4  = __attribute__((ext_vector_type(4))) float;
using us8    = __attribute__((ext_vector_type(8))) unsigned short;

typedef const __attribute__((address_space(1))) void g_void;
typedef __attribute__((address_space(3))) void lds_void;

__device__ __forceinline__ unsigned short f2bf(float f) {
  union { float f; unsigned int u; } x; x.f = f;
  unsigned int r = x.u + 0x7fffu + ((x.u >> 16) & 1u);  // RNE
  return (unsigned short)(r >> 16);
}

__device__ __forceinline__ float tanh_fast(float x) {
  // tanh(x) = 1 - 2/(exp(2x)+1); exp overflow -> +-1 naturally
  float e = __expf(2.0f * x);
  return 1.0f - 2.0f * __builtin_amdgcn_rcpf(e + 1.0f);
}

__device__ __forceinline__ void barrier_sync() {
  asm volatile("" ::: "memory");
  __builtin_amdgcn_s_barrier();
  asm volatile("" ::: "memory");
}

// ---------------- kernel 0: f32 -> bf16 convert (8 elems/thread) ----------------
__global__ __launch_bounds__(256) void cvt_kernel(const float* __restrict__ in,
                                                  unsigned short* __restrict__ out,
                                                  int n8) {
  int i = blockIdx.x * 256 + threadIdx.x;
  if (i >= n8) return;
  f32x4 a = *(const f32x4*)&in[(size_t)i * 8];
  f32x4 b = *(const f32x4*)&in[(size_t)i * 8 + 4];
  us8 o;
  #pragma unroll
  for (int j = 0; j < 4; ++j) { o[j] = f2bf(a[j]); o[j + 4] = f2bf(b[j]); }
  *(us8*)&out[(size_t)i * 8] = o;
}

// ---------------- kernel 1: pq[h] = sum_q query[q] * Wq[h,q] ----------------
__global__ __launch_bounds__(256) void pq_kernel(const float* __restrict__ query,
                                                 const float* __restrict__ Wq,
                                                 float* __restrict__ pq) {
  int wave = threadIdx.x >> 6, lane = threadIdx.x & 63;
  int h = blockIdx.x * 4 + wave;
  const float* w = Wq + (size_t)h * KDIM;
  float s = 0.f;
  for (int i = lane; i < KDIM; i += 64) s = fmaf(query[i], w[i], s);
  #pragma unroll
  for (int off = 32; off; off >>= 1) s += __shfl_xor(s, off);
  if (lane == 0) pq[h] = s;
}

// ---- kernel 2: fused scores. 256x256 tile, 8 waves (2x4), BK=64, 4-phase pipeline ----
// LDS: 2 buffers x (A[256][64] + B[256][64]) bf16 = 128 KiB, XOR-swizzled rows.
__global__ __launch_bounds__(512, 2) void scores_kernel(const unsigned short* __restrict__ keybf,
                                                        const unsigned short* __restrict__ wkbf,
                                                        const float* __restrict__ pq,
                                                        const float* __restrict__ Ws,
                                                        float* __restrict__ partial) {
  __shared__ unsigned short lds[65536];   // 128 KiB

  const int tid = threadIdx.x;
  // bijective XCD swizzle: XCD g gets 4 consecutive s-tiles x all 8 h-tiles
  const int bid = blockIdx.x;
  const int xg = bid & 7, xi = bid >> 3;
  const int bx = xg * 4 + (xi & 3);      // s-tile 0..31
  const int by = xi >> 2;                // h-tile 0..7
  const int s0 = bx * 256, h0 = by * 256;

  const int wave = tid >> 6, lane = tid & 63;
  const int wm = wave >> 2, wn = wave & 3;     // 2 x 4 waves; wave tile 128(s) x 64(h)
  const int l16 = lane & 15, g16 = lane >> 4;

  // ---- staging map: op = 64 rows x 128B; thread t -> row t>>3, 16B chunk t&7 ----
  const int srow = tid >> 3;
  const int scol = ((tid & 7) * 16) ^ ((srow & 7) << 4);   // inverse-swizzled source col
  const char* aSrc0 = (const char*)keybf + ((size_t)(s0 + srow) * KDIM) * 2 + scol;
  const char* bSrc0 = (const char*)wkbf  + ((size_t)(h0 + srow) * KDIM) * 2 + scol;

  // op o covers rows o*64..o*64+63; global row stride 64*KDIM*2 bytes
  #define STAGE_A(o, kt, buf) __builtin_amdgcn_global_load_lds( \
      (g_void*)(aSrc0 + (size_t)(o) * 64 * KDIM * 2 + (size_t)(kt) * 128), \
      (lds_void*)((char*)lds + (size_t)(buf) * 65536 + (o) * 8192 + wave * 1024), 16, 0, 0)
  #define STAGE_B(o, kt, buf) __builtin_amdgcn_global_load_lds( \
      (g_void*)(bSrc0 + (size_t)(o) * 64 * KDIM * 2 + (size_t)(kt) * 128), \
      (lds_void*)((char*)lds + (size_t)(buf) * 65536 + 32768 + (o) * 8192 + wave * 1024), 16, 0, 0)

  // ---- read-side swizzled column offsets (bytes within a 128B row) ----
  const int xorv = (l16 & 7) << 4;
  int colx[2];
  colx[0] = ((g16 * 16)      ) ^ xorv;
  colx[1] = ((g16 * 16) | 64 ) ^ xorv;
  const int aRowBase = (wm * 128 + l16) * 128;        // + m*2048
  const int bRowBase = 32768 + (wn * 64 + l16) * 128; // + n*2048

  f32x4 acc[8][4];
  #pragma unroll
  for (int m = 0; m < 8; ++m)
    #pragma unroll
    for (int n = 0; n < 4; ++n) acc[m][n] = (f32x4)(0.0f);

  // ---- prologue: stage K-tile 0 into buf 0 ----
  #pragma unroll
  for (int o = 0; o < 4; ++o) STAGE_A(o, 0, 0);
  #pragma unroll
  for (int o = 0; o < 4; ++o) STAGE_B(o, 0, 0);
  asm volatile("s_waitcnt vmcnt(0)" ::: "memory");
  barrier_sync();

  short8 af[4][2], bf_[4][2];

  for (int t = 0; t < NT; ++t) {
    const int cbase = (t & 1) * 65536;
    const int nbuf = (t & 1) ^ 1;
    const bool more = (t + 1 < NT);

    // ===== phase 0: read A(m0-3)+B(n0-1); stage next A; MFMA m0-3 x n0-1 =====
    #pragma unroll
    for (int m = 0; m < 4; ++m)
      #pragma unroll
      for (int ks = 0; ks < 2; ++ks)
        af[m][ks] = *(const short8*)((const char*)lds + cbase + aRowBase + m * 2048 + colx[ks]);
    #pragma unroll
    for (int n = 0; n < 2; ++n)
      #pragma unroll
      for (int ks = 0; ks < 2; ++ks)
        bf_[n][ks] = *(const short8*)((const char*)lds + cbase + bRowBase + n * 2048 + colx[ks]);
    if (more) {
      STAGE_A(0, t + 1, nbuf); STAGE_A(1, t + 1, nbuf);
      STAGE_A(2, t + 1, nbuf); STAGE_A(3, t + 1, nbuf);
    }
    barrier_sync();
    __builtin_amdgcn_s_setprio(1);
    #pragma unroll
    for (int m = 0; m < 4; ++m)
      #pragma unroll
      for (int n = 0; n < 2; ++n)
        #pragma unroll
        for (int ks = 0; ks < 2; ++ks)
          acc[m][n] = __builtin_amdgcn_mfma_f32_16x16x32_bf16(af[m][ks], bf_[n][ks], acc[m][n], 0, 0, 0);
    __builtin_amdgcn_s_setprio(0);
    barrier_sync();

    // ===== phase 1: read B(n2-3); stage next B; MFMA m0-3 x n2-3 =====
    #pragma unroll
    for (int n = 2; n < 4; ++n)
      #pragma unroll
      for (int ks = 0; ks < 2; ++ks)
        bf_[n][ks] = *(const short8*)((const char*)lds + cbase + bRowBase + n * 2048 + colx[ks]);
    if (more) {
      STAGE_B(0, t + 1, nbuf); STAGE_B(1, t + 1, nbuf);
      STAGE_B(2, t + 1, nbuf); STAGE_B(3, t + 1, nbuf);
    }
    barrier_sync();
    __builtin_amdgcn_s_setprio(1);
    #pragma unroll
    for (int m = 0; m < 4; ++m)
      #pragma unroll
      for (int n = 2; n < 4; ++n)
        #pragma unroll
        for (int ks = 0; ks < 2; ++ks)
          acc[m][n] = __builtin_amdgcn_mfma_f32_16x16x32_bf16(af[m][ks], bf_[n][ks], acc[m][n], 0, 0, 0);
    __builtin_amdgcn_s_setprio(0);
    barrier_sync();

    // ===== phase 2: read A(m4-7); MFMA m4-7 x n2-3 =====
    #pragma unroll
    for (int m = 0; m < 4; ++m)
      #pragma unroll
      for (int ks = 0; ks < 2; ++ks)
        af[m][ks] = *(const short8*)((const char*)lds + cbase + aRowBase + (m + 4) * 2048 + colx[ks]);
    barrier_sync();
    __builtin_amdgcn_s_setprio(1);
    #pragma unroll
    for (int m = 0; m < 4; ++m)
      #pragma unroll
      for (int n = 2; n < 4; ++n)
        #pragma unroll
        for (int ks = 0; ks < 2; ++ks)
          acc[m + 4][n] = __builtin_amdgcn_mfma_f32_16x16x32_bf16(af[m][ks], bf_[n][ks], acc[m + 4][n], 0, 0, 0);
    __builtin_amdgcn_s_setprio(0);
    barrier_sync();

    // ===== phase 3: MFMA m4-7 x n0-1 (reuse regs); then wait next buf landed =====
    __builtin_amdgcn_s_setprio(1);
    #pragma unroll
    for (int m = 0; m < 4; ++m)
      #pragma unroll
      for (int n = 0; n < 2; ++n)
        #pragma unroll
        for (int ks = 0; ks < 2; ++ks)
          acc[m + 4][n] = __builtin_amdgcn_mfma_f32_16x16x32_bf16(af[m][ks], bf_[n][ks], acc[m + 4][n], 0, 0, 0);
    __builtin_amdgcn_s_setprio(0);
    asm volatile("s_waitcnt vmcnt(0)" ::: "memory");
    barrier_sync();
  }

  // ---- epilogue: score partials. h = h0 + wn*64 + n*16 + l16 ; s = s0 + wm*128 + m*16 + g16*4 + j
  float pqv[4], wsv[4];
  #pragma unroll
  for (int n = 0; n < 4; ++n) {
    int h = h0 + wn * 64 + n * 16 + l16;
    pqv[n] = pq[h];
    wsv[n] = Ws[h];
  }

  float* sred = (float*)lds;   // [256][4] overlay
  #pragma unroll
  for (int m = 0; m < 8; ++m) {
    #pragma unroll
    for (int j = 0; j < 4; ++j) {
      float rs = 0.f;
      #pragma unroll
      for (int n = 0; n < 4; ++n)
        rs += tanh_fast(acc[m][n][j] + pqv[n]) * wsv[n];
      rs += __shfl_xor(rs, 1);
      rs += __shfl_xor(rs, 2);
      rs += __shfl_xor(rs, 4);
      rs += __shfl_xor(rs, 8);
      if (l16 == 0)
        sred[(wm * 128 + m * 16 + g16 * 4 + j) * 4 + wn] = rs;
    }
  }
  __syncthreads();
  if (tid < 256) {
    float v = sred[tid * 4 + 0] + sred[tid * 4 + 1] + sred[tid * 4 + 2] + sred[tid * 4 + 3];
    partial[(size_t)(s0 + tid) * 8 + by] = v;
  }
}

// ---------------- kernel 3: softmax over S=8192 (single block) ----------------
__global__ __launch_bounds__(1024) void softmax_kernel(const float* __restrict__ partial,
                                                       float* __restrict__ weights) {
  __shared__ float red[16];
  int tid = threadIdx.x;
  int sbase = tid * 8;
  float sc[8];
  float mx = -1e30f;
  #pragma unroll
  for (int i = 0; i < 8; ++i) {
    const float* p = partial + (size_t)(sbase + i) * 8;
    float v = 0.f;
    #pragma unroll
    for (int q = 0; q < 8; ++q) v += p[q];
    sc[i] = v;
    mx = fmaxf(mx, v);
  }
  #pragma unroll
  for (int off = 32; off; off >>= 1) mx = fmaxf(mx, __shfl_xor(mx, off));
  if ((tid & 63) == 0) red[tid >> 6] = mx;
  __syncthreads();
  float gmx = red[0];
  #pragma unroll
  for (int q = 1; q < 16; ++q) gmx = fmaxf(gmx, red[q]);
  __syncthreads();
  float ls = 0.f;
  #pragma unroll
  for (int i = 0; i < 8; ++i) { sc[i] = expf(sc[i] - gmx); ls += sc[i]; }
  #pragma unroll
  for (int off = 32; off; off >>= 1) ls += __shfl_xor(ls, off);
  if ((tid & 63) == 0) red[tid >> 6] = ls;
  __syncthreads();
  float gs = 0.f;
  #pragma unroll
  for (int q = 0; q < 16; ++q) gs += red[q];
  float inv = 1.0f / gs;
  #pragma unroll
  for (int i = 0; i < 8; ++i) weights[sbase + i] = sc[i] * inv;
}

// ---------------- kernel 4: context partials (float4, 128-row chunks) ----------------
__global__ __launch_bounds__(256) void ctx_partial_kernel(const float* __restrict__ values,
                                                          const float* __restrict__ w,
                                                          float* __restrict__ part) {
  int vcol4 = blockIdx.x * 256 + threadIdx.x;
  int ss0 = blockIdx.y * 128;
  f32x4 acc = (f32x4)(0.0f);
  for (int s = ss0; s < ss0 + 128; ++s) {
    f32x4 v = *(const f32x4*)&values[(size_t)s * VDIM + vcol4 * 4];
    float ws = w[s];
    #pragma unroll
    for (int j = 0; j < 4; ++j) acc[j] = fmaf(ws, v[j], acc[j]);
  }
  *(f32x4*)&part[(size_t)blockIdx.y * VDIM + vcol4 * 4] = acc;
}

// ---------------- kernel 5: context reduce ----------------
__global__ __launch_bounds__(256) void ctx_reduce_kernel(const float* __restrict__ part,
                                                         float* __restrict__ ctx) {
  int vcol = blockIdx.x * 256 + threadIdx.x;
  float acc = 0.f;
  #pragma unroll
  for (int p = 0; p < 64; ++p) acc += part[(size_t)p * VDIM + vcol];
  ctx[vcol] = acc;
}

extern "C" void kernel_launch(void* const* d_in, const int* in_sizes, int n_in,
                              void* d_out, int out_size, void* d_ws, size_t ws_size,
                              hipStream_t stream) {
  const float* query  = (const float*)d_in[0];
  const float* key    = (const float*)d_in[1];
  const float* values = (const float*)d_in[2];
  const float* Wq     = (const float*)d_in[3];
  const float* Wk     = (const float*)d_in[4];
  const float* Ws     = (const float*)d_in[5];

  float* out     = (float*)d_out;
  float* weights = out;          // [8192]
  float* ctx     = out + SDIM;   // [2048]

  char* ws = (char*)d_ws;
  unsigned short* keybf = (unsigned short*)ws;                              // 32 MiB
  unsigned short* wkbf  = (unsigned short*)(ws + (size_t)SDIM * KDIM * 2);  // 8 MiB
  char* tail = ws + (size_t)SDIM * KDIM * 2 + (size_t)HDIM * KDIM * 2;
  float* pq      = (float*)tail;                          // 2048 f32
  float* partial = (float*)(tail + 8192);                 // 8192*8 f32 (256 KiB)
  float* cpart   = (float*)(tail + 8192 + (size_t)SDIM * 8 * 4);  // 64*2048 f32

  cvt_kernel<<<(SDIM * KDIM / 8 + 255) / 256, 256, 0, stream>>>(key, keybf, SDIM * KDIM / 8);
  cvt_kernel<<<(HDIM * KDIM / 8 + 255) / 256, 256, 0, stream>>>(Wk, wkbf, HDIM * KDIM / 8);
  pq_kernel<<<HDIM / 4, 256, 0, stream>>>(query, Wq, pq);
  scores_kernel<<<256, 512, 0, stream>>>(keybf, wkbf, pq, Ws, partial);
  softmax_kernel<<<1, 1024, 0, stream>>>(partial, weights);
  ctx_partial_kernel<<<dim3(VDIM / (256 * 4), 64), 256, 0, stream>>>(values, weights, cpart);
  ctx_reduce_kernel<<<VDIM / 256, 256, 0, stream>>>(cpart, ctx);
}